// Round 7
// baseline (342.564 us; speedup 1.0000x reference)
//
#include <hip/hip_runtime.h>
#include <hip/hip_bf16.h>

#define TT      5
#define NHEADS  6
#define DIMC    192
#define SHIFT_  4
#define HDIM_   32
#define NTOK    320
#define NWIN    64
#define BATCH   2
#define LOG2E   1.44269504088896f
#define SCALE_LOG2E (0.17677669529663687f * 1.44269504088896f)
#define NEGMASK (-100.0f * 1.44269504088896f)

typedef short short8v __attribute__((ext_vector_type(8)));
typedef float floatx4 __attribute__((ext_vector_type(4)));
union FragU { uint4 u; short8v s; };

static __device__ __forceinline__ float bf16lo(unsigned u) {
    union { unsigned i; float f; } x; x.i = u << 16; return x.f;
}
static __device__ __forceinline__ float bf16hi(unsigned u) {
    union { unsigned i; float f; } x; x.i = u & 0xffff0000u; return x.f;
}
static __device__ __forceinline__ unsigned short bf16b(float f) {
    __hip_bfloat16 h = __float2bfloat16(f);
    unsigned short u; __builtin_memcpy(&u, &h, 2); return u;
}
static __device__ __forceinline__ unsigned pk2(float a, float b) {
    return (unsigned)bf16b(a) | ((unsigned)bf16b(b) << 16);
}
// fast half-up bf16 pair pack (P-matrix only: e >= 0, never NaN; <=1ulp bias)
static __device__ __forceinline__ unsigned pk2h(float a, float b) {
    unsigned ua = __float_as_uint(a), ub = __float_as_uint(b);
    return ((ua + 0x8000u) >> 16) | ((ub + 0x8000u) & 0xffff0000u);
}
// raw hardware 2^x (args in [-150,40] are safe; flushes to 0 below ~-126)
static __device__ __forceinline__ float fexp2(float x) {
    float r;
    asm("v_exp_f32 %0, %1" : "=v"(r) : "v"(x));
    return r;
}

// Runtime dtype sniffer (bf16-pair vs f32 data) — wave-uniform, deterministic.
static __device__ __forceinline__ bool detect_bf16(const unsigned* q) {
    uint4 w = ((const uint4*)q)[threadIdx.x & 63];
    int cnt = 0;
    unsigned e;
    e = (w.x >> 7) & 0xffu; cnt += (e >= 100u && e <= 135u);
    e = (w.y >> 7) & 0xffu; cnt += (e >= 100u && e <= 135u);
    e = (w.z >> 7) & 0xffu; cnt += (e >= 100u && e <= 135u);
    e = (w.w >> 7) & 0xffu; cnt += (e >= 100u && e <= 135u);
    unsigned long long m = __ballot(cnt >= 2);
    return __popcll(m) >= 32;
}

// ---------------------------------------------------------------------------
// Attention: 1 block per (window b_, head h), 5 waves x 64 queries.
// R7: K/V staged in TWO 160-token halves reusing the same LDS buffers.
// Rationale: occupancy counters across R5/R6 show exactly ONE block
// resident per CU at 46.6 KB LDS (behaves like a ~64 KB effective pool),
// so the latency-dominated block ran with zero inter-block overlap and
// duration was invariant to instruction mix. 23.5 KB -> >=2 blocks/CU;
// cross-block overlap hides staging + dependency-chain latency.
// launch_bounds(320,3) caps VGPR at 170 (was: compiler squeezed to 72),
// letting the scheduler keep rb/kf/vf prefetches in flight.
//
// KEY-SLOT PERMUTATION (unchanged): within each 32-key block, logical key
// l = q4*8 + kt*4 + reg sits at MFMA tile slot kt*16 + q4*4 + reg. After
// the two S^T = K*Q^T MFMAs, lane (l15,quad) holds exactly keys
// quad*8 + kt*4 + reg — the PV operand k-order — so P packs in-register.
// RPB: bias read as two float4 from precomputed rpb[h][q][k] (R6, kept).
// PV operand swap (R3, kept): oacc = (P.V)^T[dim][query] -> dwordx2 stores.
// ---------------------------------------------------------------------------
__global__ __launch_bounds__(NTOK, 3) void attn_mfma(
    const void* __restrict__ qkv_raw,
    const float* __restrict__ rpb,                 // ws: [6][320][320] f32 *LOG2E
    __hip_bfloat16* __restrict__ win_out)          // ws: [B_][320][192]
{
    const bool isbf = detect_bf16((const unsigned*)qkv_raw);
    const int b_  = blockIdx.x;       // 0..127
    const int h   = blockIdx.y;       // 0..5
    const int bb  = b_ >> 6;
    const int wdx = b_ & 63;
    const int wi  = wdx >> 3, wj = wdx & 7;
    const int tid = threadIdx.x;
    const int w    = tid >> 6;        // wave 0..4
    const int lane = tid & 63;
    const int l15  = lane & 15;
    const int quad = lane >> 4;       // 0..3
    const int g    = lane >> 3;       // segment group 0..7
    const int li   = lane & 7;        // lane within segment

    __shared__ unsigned short sK[160 * 40];    // K rows bf16 (slot-permuted), stride 40
    __shared__ unsigned short sVT[32 * 168];   // V^T [dim][local token]

    // ---- per-lane Q fragments (global only; before any LDS use) ----
    FragU qf[4];
    int labq[4];
    const float* rq[4];               // rpb row base per query-tile
    #pragma unroll
    for (int jq = 0; jq < 4; jq++) {
        const int qtok = w * 64 + jq * 16 + l15;
        const int t = qtok >> 6, s = qtok & 63, hl = s >> 3, wl = s & 7;
        rq[jq] = rpb + ((h * NTOK + qtok) * NTOK);
        const int hh = wi * 8 + hl, ww = wj * 8 + wl;
        labq[jq] = ((hh < 56) ? 0 : ((hh < 60) ? 1 : 2)) * 3 +
                   ((ww < 56) ? 0 : ((ww < 60) ? 1 : 2));
        const int gh = (wi * 8 + hl + SHIFT_) & 63;
        const int gw = (wj * 8 + wl + SHIFT_) & 63;
        const long grow = (long)bb * (TT * 64 * 64) + t * 4096 + gh * 64 + gw;
        if (!isbf) {
            const float* qp = (const float*)qkv_raw + grow * (3 * DIMC) + h * HDIM_ + quad * 8;
            qf[jq].u = make_uint4(
                pk2(qp[0]*SCALE_LOG2E, qp[1]*SCALE_LOG2E), pk2(qp[2]*SCALE_LOG2E, qp[3]*SCALE_LOG2E),
                pk2(qp[4]*SCALE_LOG2E, qp[5]*SCALE_LOG2E), pk2(qp[6]*SCALE_LOG2E, qp[7]*SCALE_LOG2E));
        } else {
            const uint4 uu = *(const uint4*)((const __hip_bfloat16*)qkv_raw + grow * (3 * DIMC) + h * HDIM_ + quad * 8);
            qf[jq].u = make_uint4(
                pk2(bf16lo(uu.x)*SCALE_LOG2E, bf16hi(uu.x)*SCALE_LOG2E),
                pk2(bf16lo(uu.y)*SCALE_LOG2E, bf16hi(uu.y)*SCALE_LOG2E),
                pk2(bf16lo(uu.z)*SCALE_LOG2E, bf16hi(uu.z)*SCALE_LOG2E),
                pk2(bf16lo(uu.w)*SCALE_LOG2E, bf16hi(uu.w)*SCALE_LOG2E));
        }
    }

    const floatx4 z4 = {0.f, 0.f, 0.f, 0.f};
    floatx4 oacc[4][2];                      // (P.V)^T: [query-tile][dim-16-tile]
    #pragma unroll
    for (int i = 0; i < 4; i++) { oacc[i][0] = z4; oacc[i][1] = z4; }
    float rs[4] = {0.f, 0.f, 0.f, 0.f};

    for (int half = 0; half < 2; half++) {
        if (half) __syncthreads();            // all waves done reading prev half

        // ---- stage this half's 160 tokens: wave w covers local tokens
        //      [w*32, w*32+32); 8-lane groups load one token's 128-B slice ----
        {
            const int btok = w * 32;
            if (!isbf) {
                const float* q32 = (const float*)qkv_raw;
                #pragma unroll
                for (int r = 0; r < 4; r++) {                // K rounds
                    const int ltok = btok + r * 8 + g;
                    const int token = half * 160 + ltok;
                    const int t = token >> 6, s = token & 63;
                    const int gh = (wi * 8 + (s >> 3) + SHIFT_) & 63;
                    const int gw = (wj * 8 + (s & 7) + SHIFT_) & 63;
                    const long grow = (long)bb * (TT * 64 * 64) + t * 4096 + gh * 64 + gw;
                    const float4 kv = *(const float4*)(q32 + grow * (3 * DIMC) + DIMC + h * HDIM_ + li * 4);
                    const int l32 = ltok & 31;
                    const int slot = (ltok & ~31) + ((l32 & 4) << 2) + ((l32 >> 3) << 2) + (l32 & 3);
                    *(uint2*)&sK[slot * 40 + li * 4] = make_uint2(pk2(kv.x, kv.y), pk2(kv.z, kv.w));
                }
                #pragma unroll
                for (int r = 0; r < 4; r++) {                // V rounds
                    const int ltok = btok + r * 8 + g;
                    const int token = half * 160 + ltok;
                    const int t = token >> 6, s = token & 63;
                    const int gh = (wi * 8 + (s >> 3) + SHIFT_) & 63;
                    const int gw = (wj * 8 + (s & 7) + SHIFT_) & 63;
                    const long grow = (long)bb * (TT * 64 * 64) + t * 4096 + gh * 64 + gw;
                    const float4 vv = *(const float4*)(q32 + grow * (3 * DIMC) + 2 * DIMC + h * HDIM_ + li * 4);
                    const int d0 = li * 4;
                    sVT[(d0 + 0) * 168 + ltok] = bf16b(vv.x);
                    sVT[(d0 + 1) * 168 + ltok] = bf16b(vv.y);
                    sVT[(d0 + 2) * 168 + ltok] = bf16b(vv.z);
                    sVT[(d0 + 3) * 168 + ltok] = bf16b(vv.w);
                }
            } else {
                const unsigned short* q16 = (const unsigned short*)qkv_raw;
                #pragma unroll
                for (int r = 0; r < 4; r++) {                // K rounds
                    const int ltok = btok + r * 8 + g;
                    const int token = half * 160 + ltok;
                    const int t = token >> 6, s = token & 63;
                    const int gh = (wi * 8 + (s >> 3) + SHIFT_) & 63;
                    const int gw = (wj * 8 + (s & 7) + SHIFT_) & 63;
                    const long grow = (long)bb * (TT * 64 * 64) + t * 4096 + gh * 64 + gw;
                    const uint2 kv = *(const uint2*)(q16 + grow * (3 * DIMC) + DIMC + h * HDIM_ + li * 4);
                    const int l32 = ltok & 31;
                    const int slot = (ltok & ~31) + ((l32 & 4) << 2) + ((l32 >> 3) << 2) + (l32 & 3);
                    *(uint2*)&sK[slot * 40 + li * 4] = kv;
                }
                #pragma unroll
                for (int r = 0; r < 4; r++) {                // V rounds
                    const int ltok = btok + r * 8 + g;
                    const int token = half * 160 + ltok;
                    const int t = token >> 6, s = token & 63;
                    const int gh = (wi * 8 + (s >> 3) + SHIFT_) & 63;
                    const int gw = (wj * 8 + (s & 7) + SHIFT_) & 63;
                    const long grow = (long)bb * (TT * 64 * 64) + t * 4096 + gh * 64 + gw;
                    const uint2 vv = *(const uint2*)(q16 + grow * (3 * DIMC) + 2 * DIMC + h * HDIM_ + li * 4);
                    const int d0 = li * 4;
                    sVT[(d0 + 0) * 168 + ltok] = (unsigned short)(vv.x & 0xffffu);
                    sVT[(d0 + 1) * 168 + ltok] = (unsigned short)(vv.x >> 16);
                    sVT[(d0 + 2) * 168 + ltok] = (unsigned short)(vv.y & 0xffffu);
                    sVT[(d0 + 3) * 168 + ltok] = (unsigned short)(vv.y >> 16);
                }
            }
        }
        __syncthreads();

        for (int kbl = 0; kbl < 5; kbl++) {
            const int kb = half * 5 + kbl;               // global key-block
            FragU kf0, kf1, vf0, vf1;
            kf0.u = *(const uint4*)&sK[(kbl * 32 + l15) * 40 + quad * 8];
            kf1.u = *(const uint4*)&sK[(kbl * 32 + 16 + l15) * 40 + quad * 8];
            vf0.u = *(const uint4*)&sVT[l15 * 168 + kbl * 32 + quad * 8];
            vf1.u = *(const uint4*)&sVT[(16 + l15) * 168 + kbl * 32 + quad * 8];

            // RPB loads: address-independent of the MFMAs -> schedulable early.
            float4 rb0[4], rb1[4];
            #pragma unroll
            for (int jq = 0; jq < 4; jq++) {
                const float* rp = rq[jq] + kb * 32 + quad * 8;
                rb0[jq] = *(const float4*)rp;
                rb1[jq] = *(const float4*)(rp + 4);
            }

            floatx4 sv0[4], sv1[4];
            #pragma unroll
            for (int jq = 0; jq < 4; jq++)
                sv0[jq] = __builtin_amdgcn_mfma_f32_16x16x32_bf16(kf0.s, qf[jq].s, z4, 0, 0, 0);
            #pragma unroll
            for (int jq = 0; jq < 4; jq++)
                sv1[jq] = __builtin_amdgcn_mfma_f32_16x16x32_bf16(kf1.s, qf[jq].s, z4, 0, 0, 0);

            // shifted-window mask labels for this lane's keys
            const int sh   = (kb & 1) * 4 + quad;
            const int rhk  = (wi == 7) ? ((sh < 4) ? 1 : 2) : 0;
            const int lab0 = rhk * 3 + ((wj == 7) ? 1 : 0);   // kt0
            const int lab1 = rhk * 3 + ((wj == 7) ? 2 : 0);   // kt1

            #pragma unroll
            for (int jq = 0; jq < 4; jq++) {
                const float m0 = (lab0 != labq[jq]) ? NEGMASK : 0.f;
                const float m1 = (lab1 != labq[jq]) ? NEGMASK : 0.f;
                float e0[4], e1[4];
                e0[0] = fexp2(sv0[jq][0] + rb0[jq].x + m0);
                e0[1] = fexp2(sv0[jq][1] + rb0[jq].y + m0);
                e0[2] = fexp2(sv0[jq][2] + rb0[jq].z + m0);
                e0[3] = fexp2(sv0[jq][3] + rb0[jq].w + m0);
                e1[0] = fexp2(sv1[jq][0] + rb1[jq].x + m1);
                e1[1] = fexp2(sv1[jq][1] + rb1[jq].y + m1);
                e1[2] = fexp2(sv1[jq][2] + rb1[jq].z + m1);
                e1[3] = fexp2(sv1[jq][3] + rb1[jq].w + m1);
                rs[jq] += ((e0[0] + e0[1]) + (e0[2] + e0[3]))
                        + ((e1[0] + e1[1]) + (e1[2] + e1[3]));
                FragU pf;
                pf.u.x = pk2h(e0[0], e0[1]); pf.u.y = pk2h(e0[2], e0[3]);
                pf.u.z = pk2h(e1[0], e1[1]); pf.u.w = pk2h(e1[2], e1[3]);
                // swapped operands: D = V^T . P^T = (P.V)^T  ->  D[dim][query]
                oacc[jq][0] = __builtin_amdgcn_mfma_f32_16x16x32_bf16(vf0.s, pf.s, oacc[jq][0], 0, 0, 0);
                oacc[jq][1] = __builtin_amdgcn_mfma_f32_16x16x32_bf16(vf1.s, pf.s, oacc[jq][1], 0, 0, 0);
            }
        }
    }

    // ---- epilogue: rs butterfly leaves every lane with the row-sum of its
    //      own l15-query; lane owns 4 consecutive dims -> dwordx2 stores ----
    unsigned short* wp = (unsigned short*)win_out;
    #pragma unroll
    for (int jq = 0; jq < 4; jq++) {
        float r = rs[jq];
        r += __shfl_xor(r, 16);
        r += __shfl_xor(r, 32);
        const float inv = 1.0f / r;
        const long ob = ((long)b_ * NTOK + (w * 64 + jq * 16 + l15)) * DIMC + h * HDIM_ + quad * 4;
        #pragma unroll
        for (int nt = 0; nt < 2; nt++) {
            const floatx4 o = oacc[jq][nt];
            *(uint2*)&wp[ob + nt * 16] =
                make_uint2(pk2(o[0] * inv, o[1] * inv), pk2(o[2] * inv, o[3] * inv));
        }
    }
}

// ---------------------------------------------------------------------------
// prep_all: one-time W -> bf16, bias -> f32, and the RPB matrix
// rpb[h][q][k] = bias_lut[cn(q)-cn(k)+112][h] * LOG2E  (f32, [6][320][320]).
// cn(n) = (n>>6)*15 + ((n>>3)&7) + (n&7); idx range [38,186] — never OOB.
// ---------------------------------------------------------------------------
__global__ __launch_bounds__(256) void prep_all(
    const void* __restrict__ w_raw, const void* __restrict__ b_raw,
    const void* __restrict__ bias_raw,
    const unsigned* __restrict__ sniff,
    unsigned short* __restrict__ wbf, float* __restrict__ bf32,
    float* __restrict__ rpb)
{
    const bool isbf = detect_bf16(sniff);
    const int gid = blockIdx.x * 256 + threadIdx.x;   // 0..102399
    if (gid < 36864) {
        if (!isbf) wbf[gid] = bf16b(((const float*)w_raw)[gid]);
        else       wbf[gid] = ((const unsigned short*)w_raw)[gid];
    }
    if (gid < 192) {
        bf32[gid] = isbf
            ? __bfloat162float(((const __hip_bfloat16*)b_raw)[gid])
            : ((const float*)b_raw)[gid];
    }
    const int q = gid / NTOK;
    const int k = gid - q * NTOK;
    const int cnq = (q >> 6) * 15 + ((q >> 3) & 7) + (q & 7);
    const int cnk = (k >> 6) * 15 + ((k >> 3) & 7) + (k & 7);
    const int idx = (cnq - cnk + 112) * NHEADS;
    #pragma unroll
    for (int h = 0; h < NHEADS; h++) {
        const float v = isbf
            ? __bfloat162float(((const __hip_bfloat16*)bias_raw)[idx + h])
            : ((const float*)bias_raw)[idx + h];
        rpb[(h * NTOK + q) * NTOK + k] = v * LOG2E;
    }
}

// ---------------------------------------------------------------------------
// Projection GEMM, zero LDS: M=64 tokens/block (4 waves x 16), N=192, K=192.
// Swapped operands: acc = mfma(W_frag, x_frag) = out^T[outdim][token].
// launch_bounds(256,4): cap 128 VGPR (default 64-cap strangled acc[12]=48
// VGPR + pipelined W/x fragments; grid 640 = 2.5 blocks/CU so 4 waves/EU
// occupancy is all that's reachable anyway).
// ---------------------------------------------------------------------------
__global__ __launch_bounds__(256, 4) void proj_mfma(
    const __hip_bfloat16* __restrict__ win,       // ws: [B_][320][192]
    const unsigned short* __restrict__ wbf,       // ws: [192][192] bf16
    const float* __restrict__ bf32,               // ws: [192] f32
    const unsigned* __restrict__ sniff,
    void* __restrict__ out_raw)                   // [B][T*64*64][192]
{
    const bool isbf = detect_bf16(sniff);
    const int tid  = threadIdx.x;
    const int w    = tid >> 6;
    const int lane = tid & 63;
    const int l15  = lane & 15;
    const int quad = lane >> 4;
    const int tok0 = blockIdx.x * 64 + w * 16;

    const floatx4 z4 = {0.f, 0.f, 0.f, 0.f};
    floatx4 acc[12];
    #pragma unroll
    for (int nt = 0; nt < 12; nt++) acc[nt] = z4;

    #pragma unroll
    for (int ks = 0; ks < 6; ks++) {
        FragU xf;
        xf.u = *(const uint4*)((const unsigned short*)win + ((long)tok0 + l15) * DIMC + ks * 32 + quad * 8);
        #pragma unroll
        for (int nt = 0; nt < 12; nt++) {
            FragU wf;
            wf.u = *(const uint4*)(wbf + (nt * 16 + l15) * DIMC + ks * 32 + quad * 8);
            // A = W rows (outdim), B = x^T (token cols) -> D[outdim][token]
            acc[nt] = __builtin_amdgcn_mfma_f32_16x16x32_bf16(wf.s, xf.s, acc[nt], 0, 0, 0);
        }
    }

    // one output-row decode per lane: token = tok0 + l15
    const int token = tok0 + l15;
    const int bw = token / NTOK;
    const int nn = token - bw * NTOK;
    const int bb = bw >> 6, wdx = bw & 63, wi2 = wdx >> 3, wj2 = wdx & 7;
    const int t = nn >> 6, s2 = nn & 63, hl = s2 >> 3, wl = s2 & 7;
    const int gh = (wi2 * 8 + hl + SHIFT_) & 63;
    const int gw = (wj2 * 8 + wl + SHIFT_) & 63;
    const long rowoff = ((long)bb * (TT * 64 * 64) + t * 4096 + gh * 64 + gw) * DIMC;

    #pragma unroll
    for (int nt = 0; nt < 12; nt++) {
        const float4 bv = *(const float4*)&bf32[nt * 16 + quad * 4];
        const float o0 = acc[nt][0] + bv.x, o1 = acc[nt][1] + bv.y;
        const float o2 = acc[nt][2] + bv.z, o3 = acc[nt][3] + bv.w;
        const long off = rowoff + nt * 16 + quad * 4;
        if (!isbf) {
            *(float4*)((float*)out_raw + off) = make_float4(o0, o1, o2, o3);
        } else {
            *(uint2*)((unsigned short*)out_raw + off) = make_uint2(pk2(o0, o1), pk2(o2, o3));
        }
    }
}

extern "C" void kernel_launch(void* const* d_in, const int* in_sizes, int n_in,
                              void* d_out, int out_size, void* d_ws, size_t ws_size,
                              hipStream_t stream)
{
    (void)in_sizes; (void)n_in; (void)out_size; (void)ws_size;
    const void* qkv        = d_in[0];
    const void* bias_table = d_in[1];
    const void* proj_w     = d_in[2];
    const void* proj_b     = d_in[3];

    __hip_bfloat16* win = (__hip_bfloat16*)d_ws;                         // 15,728,640 B
    unsigned short* wbf = (unsigned short*)((char*)d_ws + 15728640);     //     73,728 B
    float*          bfb = (float*)((char*)d_ws + 15802368);              //        768 B
    float*          rpb = (float*)((char*)d_ws + 15803136);              //  2,457,600 B

    prep_all<<<dim3(400), 256, 0, stream>>>(proj_w, proj_b, bias_table,
                                            (const unsigned*)qkv, wbf, bfb, rpb);
    attn_mfma<<<dim3(BATCH * NWIN, NHEADS), NTOK, 0, stream>>>(qkv, rpb, win);
    proj_mfma<<<dim3(BATCH * NWIN * NTOK / 64), 256, 0, stream>>>(
        win, wbf, bfb, (const unsigned*)qkv, d_out);
}

// Round 8
// 249.131 us; speedup vs baseline: 1.3750x; 1.3750x over previous
//
#include <hip/hip_runtime.h>
#include <hip/hip_bf16.h>

#define TT      5
#define NHEADS  6
#define DIMC    192
#define SHIFT_  4
#define HDIM_   32
#define NTOK    320
#define NWIN    64
#define BATCH   2
#define LOG2E   1.44269504088896f
#define SCALE_LOG2E (0.17677669529663687f * 1.44269504088896f)
#define NEGMASK (-100.0f * 1.44269504088896f)

typedef short short8v __attribute__((ext_vector_type(8)));
typedef float floatx4 __attribute__((ext_vector_type(4)));
union FragU { uint4 u; short8v s; };

static __device__ __forceinline__ float bf16lo(unsigned u) {
    union { unsigned i; float f; } x; x.i = u << 16; return x.f;
}
static __device__ __forceinline__ float bf16hi(unsigned u) {
    union { unsigned i; float f; } x; x.i = u & 0xffff0000u; return x.f;
}
static __device__ __forceinline__ unsigned short bf16b(float f) {
    __hip_bfloat16 h = __float2bfloat16(f);
    unsigned short u; __builtin_memcpy(&u, &h, 2); return u;
}
static __device__ __forceinline__ unsigned pk2(float a, float b) {
    return (unsigned)bf16b(a) | ((unsigned)bf16b(b) << 16);
}
// fast half-up bf16 pair pack (P-matrix only: e >= 0, never NaN; <=1ulp bias)
static __device__ __forceinline__ unsigned pk2h(float a, float b) {
    unsigned ua = __float_as_uint(a), ub = __float_as_uint(b);
    return ((ua + 0x8000u) >> 16) | ((ub + 0x8000u) & 0xffff0000u);
}
// raw hardware 2^x (args in [-150,40] are safe; flushes to 0 below ~-126)
static __device__ __forceinline__ float fexp2(float x) {
    float r;
    asm("v_exp_f32 %0, %1" : "=v"(r) : "v"(x));
    return r;
}

// Runtime dtype sniffer (bf16-pair vs f32 data) — wave-uniform, deterministic.
static __device__ __forceinline__ bool detect_bf16(const unsigned* q) {
    uint4 w = ((const uint4*)q)[threadIdx.x & 63];
    int cnt = 0;
    unsigned e;
    e = (w.x >> 7) & 0xffu; cnt += (e >= 100u && e <= 135u);
    e = (w.y >> 7) & 0xffu; cnt += (e >= 100u && e <= 135u);
    e = (w.z >> 7) & 0xffu; cnt += (e >= 100u && e <= 135u);
    e = (w.w >> 7) & 0xffu; cnt += (e >= 100u && e <= 135u);
    unsigned long long m = __ballot(cnt >= 2);
    return __popcll(m) >= 32;
}

// ---------------------------------------------------------------------------
// Attention: EXACT R6 kernel (proven 85 us, passed). 1 block per (window,
// head), 5 waves x 64 queries. Plain launch_bounds(320): min-waves variants
// spill catastrophically (R7: WRITE_SIZE 15->221 MB).
//
// KEY-SLOT PERMUTATION: within each 32-key block, logical key
// l = q4*8 + kt*4 + reg sits at MFMA tile slot kt*16 + q4*4 + reg. After
// the two S^T = K*Q^T MFMAs, lane (l15,quad) holds exactly keys
// quad*8 + kt*4 + reg — the PV operand k-order — so P packs in-register.
// RPB: bias read as two float4 from precomputed rpb[h][q][k].
// PV operand swap: oacc = (P.V)^T[dim][query] -> dwordx2 stores.
// ---------------------------------------------------------------------------
__global__ __launch_bounds__(NTOK) void attn_mfma(
    const void* __restrict__ qkv_raw,
    const float* __restrict__ rpb,                 // ws: [6][320][320] f32 *LOG2E
    __hip_bfloat16* __restrict__ win_out)          // ws: [B_][320][192]
{
    const bool isbf = detect_bf16((const unsigned*)qkv_raw);
    const int b_  = blockIdx.x;       // 0..127
    const int h   = blockIdx.y;       // 0..5
    const int bb  = b_ >> 6;
    const int wdx = b_ & 63;
    const int wi  = wdx >> 3, wj = wdx & 7;
    const int tid = threadIdx.x;
    const int w    = tid >> 6;        // wave 0..4
    const int lane = tid & 63;
    const int l15  = lane & 15;
    const int quad = lane >> 4;       // 0..3
    const int g    = lane >> 3;       // segment group 0..7
    const int li   = lane & 7;        // lane within segment

    __shared__ unsigned short sK[320 * 40];    // K rows bf16 (slot-permuted), stride 40
    __shared__ unsigned short sVT[32 * 328];   // V^T [dim][token]

    // ---- staging: 8-lane groups cooperatively load one token's 128-B K/V
    //      slice (fully coalesced, each segment = one aligned 128-B line) ----
    {
        const int btok = w * 64;
        if (!isbf) {
            const float* q32 = (const float*)qkv_raw;
            #pragma unroll
            for (int r = 0; r < 8; r++) {                    // K rounds
                const int token = btok + r * 8 + g;
                const int t = token >> 6, s = token & 63;
                const int gh = (wi * 8 + (s >> 3) + SHIFT_) & 63;
                const int gw = (wj * 8 + (s & 7) + SHIFT_) & 63;
                const long grow = (long)bb * (TT * 64 * 64) + t * 4096 + gh * 64 + gw;
                const float4 kv = *(const float4*)(q32 + grow * (3 * DIMC) + DIMC + h * HDIM_ + li * 4);
                const int l32 = token & 31;
                const int slot = (token & ~31) + ((l32 & 4) << 2) + ((l32 >> 3) << 2) + (l32 & 3);
                *(uint2*)&sK[slot * 40 + li * 4] = make_uint2(pk2(kv.x, kv.y), pk2(kv.z, kv.w));
            }
            #pragma unroll
            for (int r = 0; r < 8; r++) {                    // V rounds
                const int token = btok + r * 8 + g;
                const int t = token >> 6, s = token & 63;
                const int gh = (wi * 8 + (s >> 3) + SHIFT_) & 63;
                const int gw = (wj * 8 + (s & 7) + SHIFT_) & 63;
                const long grow = (long)bb * (TT * 64 * 64) + t * 4096 + gh * 64 + gw;
                const float4 vv = *(const float4*)(q32 + grow * (3 * DIMC) + 2 * DIMC + h * HDIM_ + li * 4);
                const int d0 = li * 4;
                sVT[(d0 + 0) * 328 + token] = bf16b(vv.x);
                sVT[(d0 + 1) * 328 + token] = bf16b(vv.y);
                sVT[(d0 + 2) * 328 + token] = bf16b(vv.z);
                sVT[(d0 + 3) * 328 + token] = bf16b(vv.w);
            }
        } else {
            const unsigned short* q16 = (const unsigned short*)qkv_raw;
            #pragma unroll
            for (int r = 0; r < 8; r++) {                    // K rounds
                const int token = btok + r * 8 + g;
                const int t = token >> 6, s = token & 63;
                const int gh = (wi * 8 + (s >> 3) + SHIFT_) & 63;
                const int gw = (wj * 8 + (s & 7) + SHIFT_) & 63;
                const long grow = (long)bb * (TT * 64 * 64) + t * 4096 + gh * 64 + gw;
                const uint2 kv = *(const uint2*)(q16 + grow * (3 * DIMC) + DIMC + h * HDIM_ + li * 4);
                const int l32 = token & 31;
                const int slot = (token & ~31) + ((l32 & 4) << 2) + ((l32 >> 3) << 2) + (l32 & 3);
                *(uint2*)&sK[slot * 40 + li * 4] = kv;
            }
            #pragma unroll
            for (int r = 0; r < 8; r++) {                    // V rounds
                const int token = btok + r * 8 + g;
                const int t = token >> 6, s = token & 63;
                const int gh = (wi * 8 + (s >> 3) + SHIFT_) & 63;
                const int gw = (wj * 8 + (s & 7) + SHIFT_) & 63;
                const long grow = (long)bb * (TT * 64 * 64) + t * 4096 + gh * 64 + gw;
                const uint2 vv = *(const uint2*)(q16 + grow * (3 * DIMC) + 2 * DIMC + h * HDIM_ + li * 4);
                const int d0 = li * 4;
                sVT[(d0 + 0) * 328 + token] = (unsigned short)(vv.x & 0xffffu);
                sVT[(d0 + 1) * 328 + token] = (unsigned short)(vv.x >> 16);
                sVT[(d0 + 2) * 328 + token] = (unsigned short)(vv.y & 0xffffu);
                sVT[(d0 + 3) * 328 + token] = (unsigned short)(vv.y >> 16);
            }
        }
    }

    // ---- per-lane Q fragments (B-operand: n=query=l15, k=dim=quad*8+j) ----
    FragU qf[4];
    int labq[4];
    const float* rq[4];               // rpb row base per query-tile
    #pragma unroll
    for (int jq = 0; jq < 4; jq++) {
        const int qtok = w * 64 + jq * 16 + l15;
        const int t = qtok >> 6, s = qtok & 63, hl = s >> 3, wl = s & 7;
        rq[jq] = rpb + ((h * NTOK + qtok) * NTOK);
        const int hh = wi * 8 + hl, ww = wj * 8 + wl;
        labq[jq] = ((hh < 56) ? 0 : ((hh < 60) ? 1 : 2)) * 3 +
                   ((ww < 56) ? 0 : ((ww < 60) ? 1 : 2));
        const int gh = (wi * 8 + hl + SHIFT_) & 63;
        const int gw = (wj * 8 + wl + SHIFT_) & 63;
        const long grow = (long)bb * (TT * 64 * 64) + t * 4096 + gh * 64 + gw;
        if (!isbf) {
            const float* qp = (const float*)qkv_raw + grow * (3 * DIMC) + h * HDIM_ + quad * 8;
            qf[jq].u = make_uint4(
                pk2(qp[0]*SCALE_LOG2E, qp[1]*SCALE_LOG2E), pk2(qp[2]*SCALE_LOG2E, qp[3]*SCALE_LOG2E),
                pk2(qp[4]*SCALE_LOG2E, qp[5]*SCALE_LOG2E), pk2(qp[6]*SCALE_LOG2E, qp[7]*SCALE_LOG2E));
        } else {
            const uint4 uu = *(const uint4*)((const __hip_bfloat16*)qkv_raw + grow * (3 * DIMC) + h * HDIM_ + quad * 8);
            qf[jq].u = make_uint4(
                pk2(bf16lo(uu.x)*SCALE_LOG2E, bf16hi(uu.x)*SCALE_LOG2E),
                pk2(bf16lo(uu.y)*SCALE_LOG2E, bf16hi(uu.y)*SCALE_LOG2E),
                pk2(bf16lo(uu.z)*SCALE_LOG2E, bf16hi(uu.z)*SCALE_LOG2E),
                pk2(bf16lo(uu.w)*SCALE_LOG2E, bf16hi(uu.w)*SCALE_LOG2E));
        }
    }
    __syncthreads();

    const floatx4 z4 = {0.f, 0.f, 0.f, 0.f};
    floatx4 oacc[4][2];                      // (P.V)^T: [query-tile][dim-16-tile]
    #pragma unroll
    for (int i = 0; i < 4; i++) { oacc[i][0] = z4; oacc[i][1] = z4; }
    float rs[4] = {0.f, 0.f, 0.f, 0.f};

    for (int kb = 0; kb < 10; kb++) {
        FragU kf0, kf1, vf0, vf1;
        kf0.u = *(const uint4*)&sK[(kb * 32 + l15) * 40 + quad * 8];
        kf1.u = *(const uint4*)&sK[(kb * 32 + 16 + l15) * 40 + quad * 8];
        vf0.u = *(const uint4*)&sVT[l15 * 328 + kb * 32 + quad * 8];
        vf1.u = *(const uint4*)&sVT[(16 + l15) * 328 + kb * 32 + quad * 8];

        // RPB loads: address-independent of the MFMAs -> schedulable early.
        float4 rb0[4], rb1[4];
        #pragma unroll
        for (int jq = 0; jq < 4; jq++) {
            const float* rp = rq[jq] + kb * 32 + quad * 8;
            rb0[jq] = *(const float4*)rp;
            rb1[jq] = *(const float4*)(rp + 4);
        }

        floatx4 sv0[4], sv1[4];
        #pragma unroll
        for (int jq = 0; jq < 4; jq++)
            sv0[jq] = __builtin_amdgcn_mfma_f32_16x16x32_bf16(kf0.s, qf[jq].s, z4, 0, 0, 0);
        #pragma unroll
        for (int jq = 0; jq < 4; jq++)
            sv1[jq] = __builtin_amdgcn_mfma_f32_16x16x32_bf16(kf1.s, qf[jq].s, z4, 0, 0, 0);

        // shifted-window mask labels for this lane's keys
        const int sh   = (kb & 1) * 4 + quad;
        const int rhk  = (wi == 7) ? ((sh < 4) ? 1 : 2) : 0;
        const int lab0 = rhk * 3 + ((wj == 7) ? 1 : 0);   // kt0
        const int lab1 = rhk * 3 + ((wj == 7) ? 2 : 0);   // kt1

        #pragma unroll
        for (int jq = 0; jq < 4; jq++) {
            const float m0 = (lab0 != labq[jq]) ? NEGMASK : 0.f;
            const float m1 = (lab1 != labq[jq]) ? NEGMASK : 0.f;
            float e0[4], e1[4];
            e0[0] = fexp2(sv0[jq][0] + rb0[jq].x + m0);
            e0[1] = fexp2(sv0[jq][1] + rb0[jq].y + m0);
            e0[2] = fexp2(sv0[jq][2] + rb0[jq].z + m0);
            e0[3] = fexp2(sv0[jq][3] + rb0[jq].w + m0);
            e1[0] = fexp2(sv1[jq][0] + rb1[jq].x + m1);
            e1[1] = fexp2(sv1[jq][1] + rb1[jq].y + m1);
            e1[2] = fexp2(sv1[jq][2] + rb1[jq].z + m1);
            e1[3] = fexp2(sv1[jq][3] + rb1[jq].w + m1);
            rs[jq] += ((e0[0] + e0[1]) + (e0[2] + e0[3]))
                    + ((e1[0] + e1[1]) + (e1[2] + e1[3]));
            FragU pf;
            pf.u.x = pk2h(e0[0], e0[1]); pf.u.y = pk2h(e0[2], e0[3]);
            pf.u.z = pk2h(e1[0], e1[1]); pf.u.w = pk2h(e1[2], e1[3]);
            // swapped operands: D = V^T . P^T = (P.V)^T  ->  D[dim][query]
            oacc[jq][0] = __builtin_amdgcn_mfma_f32_16x16x32_bf16(vf0.s, pf.s, oacc[jq][0], 0, 0, 0);
            oacc[jq][1] = __builtin_amdgcn_mfma_f32_16x16x32_bf16(vf1.s, pf.s, oacc[jq][1], 0, 0, 0);
        }
    }

    // ---- epilogue: rs butterfly leaves every lane with the row-sum of its
    //      own l15-query; lane owns 4 consecutive dims -> dwordx2 stores ----
    unsigned short* wp = (unsigned short*)win_out;
    #pragma unroll
    for (int jq = 0; jq < 4; jq++) {
        float r = rs[jq];
        r += __shfl_xor(r, 16);
        r += __shfl_xor(r, 32);
        const float inv = 1.0f / r;
        const long ob = ((long)b_ * NTOK + (w * 64 + jq * 16 + l15)) * DIMC + h * HDIM_ + quad * 4;
        #pragma unroll
        for (int nt = 0; nt < 2; nt++) {
            const floatx4 o = oacc[jq][nt];
            *(uint2*)&wp[ob + nt * 16] =
                make_uint2(pk2(o[0] * inv, o[1] * inv), pk2(o[2] * inv, o[3] * inv));
        }
    }
}

// ---------------------------------------------------------------------------
// prep_all R8: fully coalesced. One thread per rpb element: g = linear index
// = [h][q][k] layout exactly, so rpb[g] is a single coalesced store. First
// 36,864 threads also convert W; first 192 copy bias. Grid 2400 x 256.
// cn(n) = (n>>6)*15 + ((n>>3)&7) + (n&7); idx range [38,186] — never OOB.
// ---------------------------------------------------------------------------
__global__ __launch_bounds__(256) void prep_all(
    const void* __restrict__ w_raw, const void* __restrict__ b_raw,
    const void* __restrict__ bias_raw,
    const unsigned* __restrict__ sniff,
    unsigned short* __restrict__ wbf, float* __restrict__ bf32,
    float* __restrict__ rpb)
{
    const bool isbf = detect_bf16(sniff);
    const int g = blockIdx.x * 256 + threadIdx.x;     // 0..614399
    if (g < 36864) {
        if (!isbf) wbf[g] = bf16b(((const float*)w_raw)[g]);
        else       wbf[g] = ((const unsigned short*)w_raw)[g];
    }
    if (g < 192) {
        bf32[g] = isbf
            ? __bfloat162float(((const __hip_bfloat16*)b_raw)[g])
            : ((const float*)b_raw)[g];
    }
    const int h = g / (NTOK * NTOK);                  // 0..5
    const int r = g - h * (NTOK * NTOK);
    const int q = r / NTOK;
    const int k = r - q * NTOK;
    const int cnq = (q >> 6) * 15 + ((q >> 3) & 7) + (q & 7);
    const int cnk = (k >> 6) * 15 + ((k >> 3) & 7) + (k & 7);
    const int idx = (cnq - cnk + 112) * NHEADS + h;
    const float v = isbf
        ? __bfloat162float(((const __hip_bfloat16*)bias_raw)[idx])
        : ((const float*)bias_raw)[idx];
    rpb[g] = v * LOG2E;                               // coalesced
}

// ---------------------------------------------------------------------------
// Projection GEMM R8: M=64 tokens/block (4 waves x 16), N=192, K=192.
// NEW: the win tile (64x192 bf16, 24.6 KB) is staged into LDS with fully
// coalesced uint4 copies (consecutive lanes -> consecutive 16 B; the old
// direct xf loads touched 16 cache lines per wave instr at 384-B row
// stride). LDS stride 200 shorts (same bank-group pattern as attn's
// proven sK reads; stride 192 would be 16-way conflicted, G4).
// Swapped operands (kept): acc = mfma(W_frag, x_frag) = out^T[outdim][token].
// ---------------------------------------------------------------------------
__global__ __launch_bounds__(256) void proj_mfma(
    const __hip_bfloat16* __restrict__ win,       // ws: [B_][320][192]
    const unsigned short* __restrict__ wbf,       // ws: [192][192] bf16
    const float* __restrict__ bf32,               // ws: [192] f32
    const unsigned* __restrict__ sniff,
    void* __restrict__ out_raw)                   // [B][T*64*64][192]
{
    const bool isbf = detect_bf16(sniff);
    const int tid  = threadIdx.x;
    const int w    = tid >> 6;
    const int lane = tid & 63;
    const int l15  = lane & 15;
    const int quad = lane >> 4;
    const int tok0 = blockIdx.x * 64 + w * 16;

    __shared__ unsigned short sX[64 * 200];       // [token][dim], stride 200

    // ---- coalesced stage: 1536 uint4 total, 6 per thread ----
    {
        const unsigned short* src = (const unsigned short*)win
                                  + (long)blockIdx.x * 64 * DIMC;
        #pragma unroll
        for (int it = 0; it < 6; it++) {
            const int j   = it * 256 + tid;       // 0..1535
            const int tok = j / 24;               // 24 uint4 per 192-short row
            const int d8  = j - tok * 24;
            const uint4 v = *(const uint4*)(src + j * 8);
            *(uint4*)&sX[tok * 200 + d8 * 8] = v;
        }
    }
    __syncthreads();

    const floatx4 z4 = {0.f, 0.f, 0.f, 0.f};
    floatx4 acc[12];
    #pragma unroll
    for (int nt = 0; nt < 12; nt++) acc[nt] = z4;

    #pragma unroll
    for (int ks = 0; ks < 6; ks++) {
        FragU xf;
        xf.u = *(const uint4*)&sX[(w * 16 + l15) * 200 + ks * 32 + quad * 8];
        #pragma unroll
        for (int nt = 0; nt < 12; nt++) {
            FragU wf;
            wf.u = *(const uint4*)(wbf + (nt * 16 + l15) * DIMC + ks * 32 + quad * 8);
            // A = W rows (outdim), B = x^T (token cols) -> D[outdim][token]
            acc[nt] = __builtin_amdgcn_mfma_f32_16x16x32_bf16(wf.s, xf.s, acc[nt], 0, 0, 0);
        }
    }

    // one output-row decode per lane: token = tok0 + l15
    const int token = tok0 + l15;
    const int bw = token / NTOK;
    const int nn = token - bw * NTOK;
    const int bb = bw >> 6, wdx = bw & 63, wi2 = wdx >> 3, wj2 = wdx & 7;
    const int t = nn >> 6, s2 = nn & 63, hl = s2 >> 3, wl = s2 & 7;
    const int gh = (wi2 * 8 + hl + SHIFT_) & 63;
    const int gw = (wj2 * 8 + wl + SHIFT_) & 63;
    const long rowoff = ((long)bb * (TT * 64 * 64) + t * 4096 + gh * 64 + gw) * DIMC;

    #pragma unroll
    for (int nt = 0; nt < 12; nt++) {
        const float4 bv = *(const float4*)&bf32[nt * 16 + quad * 4];
        const float o0 = acc[nt][0] + bv.x, o1 = acc[nt][1] + bv.y;
        const float o2 = acc[nt][2] + bv.z, o3 = acc[nt][3] + bv.w;
        const long off = rowoff + nt * 16 + quad * 4;
        if (!isbf) {
            *(float4*)((float*)out_raw + off) = make_float4(o0, o1, o2, o3);
        } else {
            *(uint2*)((unsigned short*)out_raw + off) = make_uint2(pk2(o0, o1), pk2(o2, o3));
        }
    }
}

extern "C" void kernel_launch(void* const* d_in, const int* in_sizes, int n_in,
                              void* d_out, int out_size, void* d_ws, size_t ws_size,
                              hipStream_t stream)
{
    (void)in_sizes; (void)n_in; (void)out_size; (void)ws_size;
    const void* qkv        = d_in[0];
    const void* bias_table = d_in[1];
    const void* proj_w     = d_in[2];
    const void* proj_b     = d_in[3];

    __hip_bfloat16* win = (__hip_bfloat16*)d_ws;                         // 15,728,640 B
    unsigned short* wbf = (unsigned short*)((char*)d_ws + 15728640);     //     73,728 B
    float*          bfb = (float*)((char*)d_ws + 15802368);              //        768 B
    float*          rpb = (float*)((char*)d_ws + 15803136);              //  2,457,600 B

    prep_all<<<dim3(2400), 256, 0, stream>>>(proj_w, proj_b, bias_table,
                                             (const unsigned*)qkv, wbf, bfb, rpb);
    attn_mfma<<<dim3(BATCH * NWIN, NHEADS), NTOK, 0, stream>>>(qkv, rpb, win);
    proj_mfma<<<dim3(BATCH * NWIN * NTOK / 64), 256, 0, stream>>>(
        win, wbf, bfb, (const unsigned*)qkv, d_out);
}